// Round 19
// baseline (217.116 us; speedup 1.0000x reference)
//
#include <hip/hip_runtime.h>
#include <hip/hip_bf16.h>
#include <climits>

// ---------------------------------------------------------------------------
// RelativeMultiHeadAttentionBlock (Transformer-XL style) on MI355X (gfx950)
// B=2, T=C=1024, M=1024, S=2048, H=16, HD=64, F=1024. fp32 in/out, bf16 MFMA.
//
// R18: attn LDS diet. ldsV (16KB dbuf) removed: V fragments are block-shared
// L2-resident reads; they are now batch-loaded from global right before the
// softmax VALU block (latency hidden under ~600cy of softmax math). LDS
// 40KB -> 24KB raises the residency ceiling 4 -> 6 blocks/CU and halves
// staging work. Everything else identical to R17 (best: 180.7us).
// ---------------------------------------------------------------------------

typedef unsigned short u16;
typedef short bf16x8 __attribute__((ext_vector_type(8)));
typedef float f32x4 __attribute__((ext_vector_type(4)));

__device__ __forceinline__ f32x4 mfma16x16x32(bf16x8 a, bf16x8 b, f32x4 c) {
  return __builtin_amdgcn_mfma_f32_16x16x32_bf16(a, b, c, 0, 0, 0);
}

__device__ __forceinline__ u16 f2bf(float f) {  // RNE via HW cvt
  __hip_bfloat16 h = __float2bfloat16(f);
  return *reinterpret_cast<u16*>(&h);
}

__device__ __forceinline__ float bf2f(u16 x) {
  unsigned u = ((unsigned)x) << 16;
  return __builtin_bit_cast(float, u);
}

__device__ __forceinline__ void gll16(const void* g, void* l) {
  __builtin_amdgcn_global_load_lds(
      (const __attribute__((address_space(1))) void*)g,
      (__attribute__((address_space(3))) void*)l, 16, 0, 0);
}

// DPP 16-lane rotation allreduce (VALU pipe; rows of 16 = our gq groups)
template <int CTRL>
__device__ __forceinline__ float rot16(float x) {
  int i = __builtin_bit_cast(int, x);
  int r = __builtin_amdgcn_update_dpp(i, i, CTRL, 0xF, 0xF, false);
  return __builtin_bit_cast(float, r);
}
__device__ __forceinline__ float dpp_max16(float x) {
  x = fmaxf(x, rot16<0x128>(x));  // ror:8
  x = fmaxf(x, rot16<0x124>(x));  // ror:4
  x = fmaxf(x, rot16<0x122>(x));  // ror:2
  x = fmaxf(x, rot16<0x121>(x));  // ror:1
  return x;
}
__device__ __forceinline__ float dpp_sum16(float x) {
  x += rot16<0x128>(x);
  x += rot16<0x124>(x);
  x += rot16<0x122>(x);
  x += rot16<0x121>(x);
  return x;
}

// --- segment ids ------------------------------------------------------------
__global__ __launch_bounds__(64) void seg_scan_kernel(
    const int* __restrict__ mask, const int* __restrict__ mem_mask,
    const int* __restrict__ cache_mask, int* __restrict__ qseg,
    int* __restrict__ kseg) {
  __shared__ int cs[3072];
  int b = blockIdx.x, lane = threadIdx.x;
  int carry = 0;
  for (int base = 0; base < 3072; base += 64) {
    int idx = base + lane;
    int val;
    if (idx < 1024)      val = mem_mask[b * 1024 + idx];
    else if (idx < 2048) val = cache_mask[b * 1024 + idx - 1024];
    else                 val = mask[b * 1024 + idx - 2048];
    for (int o = 1; o < 64; o <<= 1) {
      int n = __shfl_up(val, o);
      if (lane >= o) val += n;
    }
    val += carry;
    cs[idx] = val;
    carry = __shfl(val, 63);
  }
  __syncthreads();
  int mx = INT_MIN;
  for (int i = lane; i < 2048; i += 64) mx = max(mx, cs[i]);
  for (int o = 1; o < 64; o <<= 1) mx = max(mx, __shfl_xor(mx, o));
  int cs2047 = cs[2047];
  for (int t = lane; t < 1024; t += 64) qseg[b * 1024 + t] = cs[2048 + t] - cs2047 + mx;
  for (int j = lane; j < 2048; j += 64) kseg[b * 2048 + j] = cs[1024 + j];
}

// --- fused prep: [0,4096)=cvt x/rel  [4096,9216)=W^T x5
//                 [9216,11264)=cache_key perm  [11264,13312)=cache_value tr
__global__ __launch_bounds__(256) void prep_kernel(
    const float* __restrict__ x, u16* __restrict__ xbf,
    const float* __restrict__ rel, u16* __restrict__ relbf,
    const float* __restrict__ Wq, const float* __restrict__ Wk,
    const float* __restrict__ Wv, const float* __restrict__ Wr,
    const float* __restrict__ Wo, u16* __restrict__ wt5,
    const float* __restrict__ cache_key, u16* __restrict__ kbuf,
    const float* __restrict__ cache_value, u16* __restrict__ vtbuf) {
  __shared__ float tile[32][33];
  const int bid = blockIdx.x, tid = threadIdx.x;
  if (bid < 4096) {  // cvt x + rel_emb -> bf16
    int q = bid * 256 + tid;
    const float* s;
    u16* d;
    int i;
    if (q < 524288) { s = x; d = xbf; i = q * 4; }
    else            { s = rel; d = relbf; i = (q - 524288) * 4; }
    float4 v = *(const float4*)(s + i);
    d[i + 0] = f2bf(v.x); d[i + 1] = f2bf(v.y);
    d[i + 2] = f2bf(v.z); d[i + 3] = f2bf(v.w);
  } else if (bid < 9216) {  // 5 weight transposes
    int t = bid - 4096;
    int z = t >> 10, rem = t & 1023;
    int bx = rem & 31, byy = rem >> 5;
    const float* src = (z == 0) ? Wq : (z == 1) ? Wk : (z == 2) ? Wv
                       : (z == 3) ? Wr : Wo;
    u16* dst = wt5 + ((size_t)z << 20);
    int tx = tid & 31, ty = tid >> 5;
    int r0 = byy * 32, c0 = bx * 32;
#pragma unroll
    for (int i = 0; i < 32; i += 8)
      tile[ty + i][tx] = src[(size_t)(r0 + ty + i) * 1024 + c0 + tx];
    __syncthreads();
#pragma unroll
    for (int i = 0; i < 32; i += 8)
      dst[(size_t)(c0 + ty + i) * 1024 + r0 + tx] = f2bf(tile[tx][ty + i]);
  } else if (bid < 11264) {  // cache_key (b,t,h,d) -> kbuf[b][h][t][d]
    int i = (bid - 9216) * 256 + tid;  // 524288 quads
    int dq = i & 15, h = (i >> 4) & 15, t = (i >> 8) & 1023, b = i >> 18;
    float4 v = *(const float4*)(cache_key + (size_t)i * 4);
    size_t o = (((size_t)(b * 16 + h)) * 2048 + t) * 64 + dq * 4;
    kbuf[o + 0] = f2bf(v.x); kbuf[o + 1] = f2bf(v.y);
    kbuf[o + 2] = f2bf(v.z); kbuf[o + 3] = f2bf(v.w);
  } else {  // cache_value (b,t,h,d) -> vtbuf[b][h][d][t]
    int t = bid - 11264;  // dims (32, 2, 32): x fastest
    int x0 = t & 31, y0 = (t >> 5) & 1, z0 = t >> 6;
    int bh = z0, b = bh >> 4, h = bh & 15;
    int t0 = x0 * 32, d0 = y0 * 32;
    int tx = tid & 31, ty = tid >> 5;
#pragma unroll
    for (int i = 0; i < 32; i += 8)
      tile[ty + i][tx] =
          cache_value[(((size_t)b * 1024 + t0 + ty + i) * 16 + h) * 64 + d0 + tx];
    __syncthreads();
#pragma unroll
    for (int i = 0; i < 32; i += 8)
      vtbuf[((size_t)bh * 64 + d0 + ty + i) * 2048 + t0 + tx] = f2bf(tile[tx][ty + i]);
  }
}

// --- projection GEMM (modes 0-3): 128x128 tile, BK=64, 4 waves --------------
__global__ __launch_bounds__(256, 2) void gemm_proj_kernel(
    const u16* __restrict__ xbf, const u16* __restrict__ relbf,
    const u16* __restrict__ wt5, u16* __restrict__ qu, u16* __restrict__ qv,
    u16* __restrict__ kbuf, u16* __restrict__ vtbuf, u16* __restrict__ rbuf,
    float* __restrict__ dout, const float* __restrict__ uvec,
    const float* __restrict__ vvec) {
  __shared__ __align__(16) u16 lA[128 * 64];
  __shared__ __align__(16) u16 lB[128 * 64];
  const int mode = (int)blockIdx.z;
  const u16* A = (mode == 3) ? relbf : xbf;
  const u16* Wm = wt5 + (size_t)mode * 1048576;
  const int tid = threadIdx.x;
  const int lane = tid & 63, gq = lane >> 4, cl = lane & 15;
  const int wv = tid >> 6, wm = wv >> 1, wn = wv & 1;
  const int by = blockIdx.y * 128, bx = blockIdx.x * 128;
  const f32x4 fz = {0.f, 0.f, 0.f, 0.f};

  f32x4 acc[4][4];
#pragma unroll
  for (int mi = 0; mi < 4; ++mi)
#pragma unroll
    for (int ni = 0; ni < 4; ++ni) acc[mi][ni] = fz;

  int offs[4];
  const u16 *pA[4], *pB[4];
#pragma unroll
  for (int c = 0; c < 4; ++c) {
    int off = tid * 16 + c * 4096;
    int L = off ^ (((off >> 7) & 7) << 4);
    int rr = off >> 7, ke = (L & 127) >> 1;
    offs[c] = off;
    pA[c] = A + (size_t)(by + rr) * 1024 + ke;
    pB[c] = Wm + (size_t)(bx + rr) * 1024 + ke;
  }

  for (int k0 = 0; k0 < 1024; k0 += 64) {
#pragma unroll
    for (int c = 0; c < 4; ++c) {
      gll16(pA[c] + k0, (char*)lA + offs[c]);
      gll16(pB[c] + k0, (char*)lB + offs[c]);
    }
    __syncthreads();
    bf16x8 af[4][2], bff[4][2];
#pragma unroll
    for (int mi = 0; mi < 4; ++mi)
#pragma unroll
      for (int kb = 0; kb < 2; ++kb) {
        int row = wm * 64 + mi * 16 + cl;
        int byte = row * 128 + kb * 64 + gq * 16;
        byte ^= ((row & 7) << 4);
        af[mi][kb] = *(const bf16x8*)((const char*)lA + byte);
      }
#pragma unroll
    for (int ni = 0; ni < 4; ++ni)
#pragma unroll
      for (int kb = 0; kb < 2; ++kb) {
        int row = wn * 64 + ni * 16 + cl;
        int byte = row * 128 + kb * 64 + gq * 16;
        byte ^= ((row & 7) << 4);
        bff[ni][kb] = *(const bf16x8*)((const char*)lB + byte);
      }
#pragma unroll
    for (int mi = 0; mi < 4; ++mi)
#pragma unroll
      for (int ni = 0; ni < 4; ++ni) {
        acc[mi][ni] = mfma16x16x32(af[mi][0], bff[ni][0], acc[mi][ni]);
        acc[mi][ni] = mfma16x16x32(af[mi][1], bff[ni][1], acc[mi][ni]);
      }
    __syncthreads();
  }

  const float SC = 0.18033688011112042f;  // 0.125 * log2(e)
#pragma unroll
  for (int mi = 0; mi < 4; ++mi)
#pragma unroll
    for (int ni = 0; ni < 4; ++ni) {
      int n = bx + wn * 64 + ni * 16 + cl;
      float ub = 0.f, vb = 0.f;
      if (mode == 0) { ub = uvec[n]; vb = vvec[n]; }
#pragma unroll
      for (int r = 0; r < 4; ++r) {
        int m = by + wm * 64 + mi * 16 + 4 * gq + r;
        float val = acc[mi][ni][r];
        if (mode == 0) {
          qu[(size_t)m * 1024 + n] = f2bf((val + ub) * SC);
          qv[(size_t)m * 1024 + n] = f2bf((val + vb) * SC);
        } else if (mode == 1) {
          dout[2097152 + (size_t)m * 1024 + n] = val;
          kbuf[(((size_t)((m >> 10) * 16 + (n >> 6))) * 2048 + 1024 + (m & 1023)) * 64 +
               (n & 63)] = f2bf(val);
        } else if (mode == 2) {
          dout[4194304 + (size_t)m * 1024 + n] = val;
          vtbuf[(((size_t)((m >> 10) * 16 + (n >> 6))) * 64 + (n & 63)) * 2048 + 1024 +
                (m & 1023)] = f2bf(val);
        } else {
          rbuf[((size_t)(n >> 6) * 2048 + m) * 64 + (n & 63)] = f2bf(val);
        }
      }
    }
}

// --- output GEMM (o @ Wo): 64x64 tile, 4 waves (2x2), 512 blocks ------------
__global__ __launch_bounds__(256, 2) void gemm_o_kernel(
    const u16* __restrict__ obf, const u16* __restrict__ wo,
    float* __restrict__ dout) {
  __shared__ __align__(16) u16 lA[64 * 64];
  __shared__ __align__(16) u16 lB[64 * 64];
  const int tid = threadIdx.x;
  const int lane = tid & 63, gq = lane >> 4, cl = lane & 15;
  const int wv = tid >> 6, wm = wv >> 1, wn = wv & 1;
  const int by = blockIdx.y * 64, bx = blockIdx.x * 64;
  const f32x4 fz = {0.f, 0.f, 0.f, 0.f};

  f32x4 acc[2][2];
#pragma unroll
  for (int a = 0; a < 2; ++a)
#pragma unroll
    for (int bq = 0; bq < 2; ++bq) acc[a][bq] = fz;

  const int off0 = tid * 16, off1 = tid * 16 + 4096;
  const int L0 = off0 ^ (((off0 >> 7) & 7) << 4);
  const int L1 = off1 ^ (((off1 >> 7) & 7) << 4);
  const int rr0 = off0 >> 7, ke0 = (L0 & 127) >> 1;
  const int rr1 = off1 >> 7, ke1 = (L1 & 127) >> 1;
  const u16* pA0 = obf + (size_t)(by + rr0) * 1024 + ke0;
  const u16* pA1 = obf + (size_t)(by + rr1) * 1024 + ke1;
  const u16* pB0 = wo + (size_t)(bx + rr0) * 1024 + ke0;
  const u16* pB1 = wo + (size_t)(bx + rr1) * 1024 + ke1;

  for (int k0 = 0; k0 < 1024; k0 += 64) {
    gll16(pA0 + k0, (char*)lA + off0);
    gll16(pA1 + k0, (char*)lA + off1);
    gll16(pB0 + k0, (char*)lB + off0);
    gll16(pB1 + k0, (char*)lB + off1);
    __syncthreads();
    bf16x8 af[2][2], bff[2][2];
#pragma unroll
    for (int mi = 0; mi < 2; ++mi)
#pragma unroll
      for (int kb = 0; kb < 2; ++kb) {
        int row = wm * 32 + mi * 16 + cl;
        int byte = row * 128 + kb * 64 + gq * 16;
        byte ^= ((row & 7) << 4);
        af[mi][kb] = *(const bf16x8*)((const char*)lA + byte);
      }
#pragma unroll
    for (int ni = 0; ni < 2; ++ni)
#pragma unroll
      for (int kb = 0; kb < 2; ++kb) {
        int row = wn * 32 + ni * 16 + cl;
        int byte = row * 128 + kb * 64 + gq * 16;
        byte ^= ((row & 7) << 4);
        bff[ni][kb] = *(const bf16x8*)((const char*)lB + byte);
      }
#pragma unroll
    for (int mi = 0; mi < 2; ++mi)
#pragma unroll
      for (int ni = 0; ni < 2; ++ni) {
        acc[mi][ni] = mfma16x16x32(af[mi][0], bff[ni][0], acc[mi][ni]);
        acc[mi][ni] = mfma16x16x32(af[mi][1], bff[ni][1], acc[mi][ni]);
      }
    __syncthreads();
  }

#pragma unroll
  for (int mi = 0; mi < 2; ++mi)
#pragma unroll
    for (int ni = 0; ni < 2; ++ni) {
      int n = bx + wn * 32 + ni * 16 + cl;
#pragma unroll
      for (int r = 0; r < 4; ++r) {
        int m = by + wm * 32 + mi * 16 + 4 * gq + r;
        dout[(size_t)m * 1024 + n] = acc[mi][ni][r];
      }
    }
}

// --- flash attention: 4-wave cooperative block (64 q-rows), K-only staging --
// grid (64 = qt*4 + chunk, 32 = bh); 4-way key split; LDS 24KB; V direct L2.
__global__ __launch_bounds__(256, 2) void attn_kernel(
    const u16* __restrict__ qu, const u16* __restrict__ qv,
    const u16* __restrict__ kbuf, const u16* __restrict__ vtbuf,
    const u16* __restrict__ rbuf, const int* __restrict__ qseg,
    const int* __restrict__ kseg, u16* __restrict__ pO,
    float* __restrict__ pml) {
  __shared__ __align__(16) u16 ldsK[2][64 * 64];  // [buf][s-row][d], swizzled
  __shared__ __align__(16) u16 ldsP[4][16 * 64];  // per-wave P

  const int tid = threadIdx.x, lane = tid & 63;
  const int gq = lane >> 4, cl = lane & 15;
  const int wv = tid >> 6;
  // XCD-locality remap (bijective over 2048): 4 (b,h) per XCD
  int lin = blockIdx.x + 64 * blockIdx.y;
  lin = (lin & 7) * 256 + (lin >> 3);
  const int bh = lin >> 6, xx = lin & 63;
  const int qt = xx >> 2, chunk = xx & 3;
  const int b = bh >> 4, h = bh & 15;
  const int i0b = qt * 64;            // block's first q-row
  const int i0 = i0b + wv * 16;       // this wave's first q-row
  const int tmax = (i0b + 63 + 1024) >> 6;  // block-uniform
  const f32x4 fz = {0.f, 0.f, 0.f, 0.f};

  const u16* rbh = rbuf + (size_t)h * 2048 * 64;
  const int* ksegb = kseg + (size_t)b * 2048;

  // staging: linear LDS dest, pre-swizzled global source (involution)
  const u16* Kbase = kbuf + (size_t)bh * 2048 * 64;
  const u16* Vbase = vtbuf + (size_t)bh * 64 * 2048;  // [d][s], read direct
  const int offc0 = tid * 16, offc1 = tid * 16 + 4096;
  const int L0s = offc0 ^ (((offc0 >> 7) & 7) << 4);
  const int L1s = offc1 ^ (((offc1 >> 7) & 7) << 4);
  const u16* kS0 = Kbase + (size_t)(offc0 >> 7) * 64 + ((L0s & 127) >> 1);
  const u16* kS1 = Kbase + (size_t)(offc1 >> 7) * 64 + ((L1s & 127) >> 1);

#define STAGE(T, B)                                                \
  do {                                                             \
    gll16(kS0 + (size_t)(T) * 4096, (char*)ldsK[B] + offc0);       \
    gll16(kS1 + (size_t)(T) * 4096, (char*)ldsK[B] + offc1);       \
  } while (0)

  STAGE(chunk, 0);  // prologue prefetch (in flight during Q setup)

  // Q fragments (pre-scaled by 0.125*log2e): row=cl, k=32*kb+8*gq+j
  bf16x8 aU[2], aV[2];
#pragma unroll
  for (int kb = 0; kb < 2; ++kb) {
    size_t off = ((size_t)b * 1024 + i0 + cl) * 1024 + h * 64 + kb * 32 + gq * 8;
    aU[kb] = *(const bf16x8*)(qu + off);
    aV[kb] = *(const bf16x8*)(qv + off);
  }
  // loop-invariant per-row constants
  int qsv[4], srcl[4], athr[4];
  bool sel[4];
#pragma unroll
  for (int r = 0; r < 4; ++r) {
    int ri = 4 * gq + r;
    qsv[r] = qseg[b * 1024 + i0 + ri];
    int lc = cl - ri + 15;  // in [0,30]
    srcl[r] = (gq << 4) | (lc & 15);
    sel[r] = (lc < 16);
    athr[r] = i0 + ri + 1024 - cl;  // causal: j0t+16jt <= athr
  }

  float mrun[4], lrun[4];
  f32x4 oacc[4];
#pragma unroll
  for (int r = 0; r < 4; ++r) { mrun[r] = -1e30f; lrun[r] = 0.f; }
#pragma unroll
  for (int di = 0; di < 4; ++di) oacc[di] = fz;

  __syncthreads();  // staging of first tile complete

  int bufi = 0;
  for (int t = chunk; t <= tmax; t += 4, bufi ^= 1) {
    if (t + 4 <= tmax) STAGE(t + 4, bufi ^ 1);  // overlaps with compute below
    const int j0t = t * 64;
    const int Rb0 = j0t - i0 + 1008;  // 16-aligned band base, >= 0
    const bool interior = (j0t + 63 <= i0 + 1024);  // wave-uniform causal skip
    // ---- per-wave global loads: r bands + kseg, batch-issued + fenced ----
    bf16x8 Rf[5][2];
#pragma unroll
    for (int p = 0; p < 5; ++p) {
      const u16* rp = rbh + (size_t)min(Rb0 + 16 * p + cl, 2047) * 64 + gq * 8;
      Rf[p][0] = *(const bf16x8*)rp;
      Rf[p][1] = *(const bf16x8*)(rp + 32);
    }
    int ksv[4];
#pragma unroll
    for (int jt = 0; jt < 4; ++jt) ksv[jt] = ksegb[j0t + 16 * jt + cl];
    __builtin_amdgcn_sched_barrier(0);

    const char* Kl = (const char*)ldsK[bufi];
    // ---- QK^T from LDS ----
    __builtin_amdgcn_s_setprio(1);
    f32x4 xq[4];
#pragma unroll
    for (int jt = 0; jt < 4; ++jt) {
      int row = jt * 16 + cl;
      int sw = (row & 7) << 4;
      bf16x8 k0 = *(const bf16x8*)(Kl + ((row * 128 + gq * 16) ^ sw));
      bf16x8 k1 = *(const bf16x8*)(Kl + ((row * 128 + 64 + gq * 16) ^ sw));
      f32x4 a = mfma16x16x32(aU[0], k0, fz);
      xq[jt] = mfma16x16x32(aU[1], k1, a);
    }
    // ---- bias-band MFMAs (bands shared: bd1[jt] == bd0[jt+1]) ----
    f32x4 bb[5];
#pragma unroll
    for (int p = 0; p < 5; ++p) {
      f32x4 a = mfma16x16x32(aV[0], Rf[p][0], fz);
      bb[p] = mfma16x16x32(aV[1], Rf[p][1], a);
    }
    __builtin_amdgcn_s_setprio(0);
    // ---- diagonal gather: 20 independent bpermutes, batch-issued ----
    float D[5][4];
#pragma unroll
    for (int p = 0; p < 5; ++p)
#pragma unroll
      for (int r = 0; r < 4; ++r) D[p][r] = __shfl(bb[p][r], srcl[r]);
    __builtin_amdgcn_sched_barrier(0);

    // ---- V fragments direct from L2, batch-issued; latency hides under
    //      the softmax VALU block below ----
    bf16x8 Vf[4][2];
#pragma unroll
    for (int di = 0; di < 4; ++di) {
      const u16* vp = Vbase + (size_t)(di * 16 + cl) * 2048 + j0t + gq * 8;
      Vf[di][0] = *(const bf16x8*)vp;
      Vf[di][1] = *(const bf16x8*)(vp + 32);
    }
    __builtin_amdgcn_sched_barrier(0);

    // ---- scores + mask (exp2 domain) ----
    float x[4][4];
#pragma unroll
    for (int jt = 0; jt < 4; ++jt)
#pragma unroll
      for (int r = 0; r < 4; ++r) {
        float bdv = sel[r] ? D[jt][r] : D[jt + 1][r];
        bool ok = (interior || (j0t + 16 * jt <= athr[r])) && (ksv[jt] == qsv[r]);
        x[jt][r] = ok ? (xq[jt][r] + bdv) : -1e30f;
      }

    // ---- online softmax (DPP allreduce; exp2) ----
    char* Pm = (char*)ldsP[wv];
    float alf[4];
#pragma unroll
    for (int r = 0; r < 4; ++r) {
      float mx = fmaxf(fmaxf(x[0][r], x[1][r]), fmaxf(x[2][r], x[3][r]));
      mx = dpp_max16(mx);
      float mold = mrun[r];
      float mnew = fmaxf(mold, mx);
      float al = exp2f(mold - mnew);
      float p0 = exp2f(x[0][r] - mnew);
      float p1 = exp2f(x[1][r] - mnew);
      float p2 = exp2f(x[2][r] - mnew);
      float p3 = exp2f(x[3][r] - mnew);
      float s = dpp_sum16(p0 + p1 + p2 + p3);
      mrun[r] = mnew;
      lrun[r] = lrun[r] * al + s;
      alf[r] = al;
      int ri = 4 * gq + r;
      int bbx = (ri & 7) << 4;
      *(u16*)(Pm + ((ri * 128 + cl * 2) ^ bbx)) = f2bf(p0);
      *(u16*)(Pm + ((ri * 128 + (16 + cl) * 2) ^ bbx)) = f2bf(p1);
      *(u16*)(Pm + ((ri * 128 + (32 + cl) * 2) ^ bbx)) = f2bf(p2);
      *(u16*)(Pm + ((ri * 128 + (48 + cl) * 2) ^ bbx)) = f2bf(p3);
    }
    f32x4 av = {alf[0], alf[1], alf[2], alf[3]};
#pragma unroll
    for (int di = 0; di < 4; ++di) oacc[di] *= av;
    // ---- PV: P round-trip (same wave), V already in regs ----
    int psw = (cl & 7) << 4;
    bf16x8 pf0 = *(const bf16x8*)(Pm + ((cl * 128 + gq * 16) ^ psw));
    bf16x8 pf1 = *(const bf16x8*)(Pm + ((cl * 128 + 64 + gq * 16) ^ psw));
    __builtin_amdgcn_s_setprio(1);
#pragma unroll
    for (int di = 0; di < 4; ++di) {
      oacc[di] = mfma16x16x32(pf0, Vf[di][0], oacc[di]);
      oacc[di] = mfma16x16x32(pf1, Vf[di][1], oacc[di]);
    }
    __builtin_amdgcn_s_setprio(0);
    __syncthreads();  // staging(t+4) landed; protects both K buffers
  }
#undef STAGE

  // epilogue: raw partials (no 1/l) + (m,l); non-temporal (protect L2 reads)
#pragma unroll
  for (int r = 0; r < 4; ++r) {
    int iq = i0 + 4 * gq + r;
    size_t rowp = ((size_t)bh * 4 + chunk) * 1024 + iq;
#pragma unroll
    for (int di = 0; di < 4; ++di)
      __builtin_nontemporal_store(f2bf(oacc[di][r]), &pO[rowp * 64 + di * 16 + cl]);
    if (cl == 0) {
      __builtin_nontemporal_store(mrun[r], &pml[rowp * 2]);
      __builtin_nontemporal_store(lrun[r], &pml[rowp * 2 + 1]);
    }
  }
}

// --- split-key combine (4 chunks, exp2 domain) ------------------------------
__global__ __launch_bounds__(256) void combine_kernel(
    const u16* __restrict__ pO, const float* __restrict__ pml,
    u16* __restrict__ obf) {
  int gid = blockIdx.x * 256 + threadIdx.x;  // 262144
  int d8 = (gid & 7) * 8;
  int row = gid >> 3;  // bh*1024 + iq
  int bh = row >> 10, iq = row & 1023;
  int b = bh >> 4, h = bh & 15;
  size_t rbase = (size_t)bh * 4 * 1024 + iq;
  float m[4], l[4], w[4];
  float ms = -1e30f;
#pragma unroll
  for (int c = 0; c < 4; ++c) {
    m[c] = pml[(rbase + c * 1024) * 2];
    l[c] = pml[(rbase + c * 1024) * 2 + 1];
    ms = fmaxf(ms, m[c]);
  }
  float den = 0.f;
#pragma unroll
  for (int c = 0; c < 4; ++c) { w[c] = exp2f(m[c] - ms); den += l[c] * w[c]; }
  float inv = 1.0f / fmaxf(den, 1e-30f);
  float acc[8] = {0, 0, 0, 0, 0, 0, 0, 0};
#pragma unroll
  for (int c = 0; c < 4; ++c) {
    bf16x8 a = *(const bf16x8*)(pO + (rbase + c * 1024) * 64 + d8);
#pragma unroll
    for (int j = 0; j < 8; ++j) acc[j] += bf2f((u16)a[j]) * w[c];
  }
  bf16x8 o;
#pragma unroll
  for (int j = 0; j < 8; ++j) o[j] = (short)f2bf(acc[j] * inv);
  *(bf16x8*)(obf + ((size_t)b * 1024 + iq) * 1024 + h * 64 + d8) = o;
}

// ---------------------------------------------------------------------------
extern "C" void kernel_launch(void* const* d_in, const int* in_sizes, int n_in,
                              void* d_out, int out_size, void* d_ws, size_t ws_size,
                              hipStream_t stream) {
  (void)in_sizes; (void)n_in; (void)out_size; (void)ws_size;
  const float* x           = (const float*)d_in[0];
  const int*   mask        = (const int*)d_in[1];
  const int*   mem_mask    = (const int*)d_in[3];
  const float* cache_key   = (const float*)d_in[4];
  const float* cache_value = (const float*)d_in[5];
  const int*   cache_mask  = (const int*)d_in[6];
  const float* rel_emb     = (const float*)d_in[7];
  const float* Wq          = (const float*)d_in[8];
  const float* Wk          = (const float*)d_in[9];
  const float* Wv          = (const float*)d_in[10];
  const float* Wr          = (const float*)d_in[11];
  const float* uvec        = (const float*)d_in[12];
  const float* vvec        = (const float*)d_in[13];
  const float* Wo          = (const float*)d_in[14];
  float* dout = (float*)d_out;

  char* W = (char*)d_ws;  // ~51.1 MB of workspace used
  u16* xbf   = (u16*)(W + (0u << 20));   // dead after projection GEMMs
  u16* relbf = (u16*)(W + (4u << 20));   // dead after projection GEMMs
  u16* pO    = (u16*)(W + (0u << 20));   // 16MB: overlays xbf,relbf,wt5[0..3]
  u16* wt5   = (u16*)(W + (8u << 20));   // q,k,v,r dead by attn; o at +8MB
  u16* kbuf  = (u16*)(W + (18u << 20));
  u16* vtbuf = (u16*)(W + (26u << 20));
  u16* rbuf  = (u16*)(W + (34u << 20));
  u16* qu    = (u16*)(W + (38u << 20));
  u16* qv    = (u16*)(W + (42u << 20));
  u16* obf   = (u16*)(W + (46u << 20));
  int* qseg  = (int*)(W + (50u << 20));
  int* kseg  = (int*)(W + (50u << 20) + 8192);
  float* pml = (float*)(W + (50u << 20) + 32768);

  seg_scan_kernel<<<dim3(2), dim3(64), 0, stream>>>(mask, mem_mask, cache_mask, qseg, kseg);
  prep_kernel<<<dim3(13312), dim3(256), 0, stream>>>(
      x, xbf, rel_emb, relbf, Wq, Wk, Wv, Wr, Wo, wt5, cache_key, kbuf,
      cache_value, vtbuf);
  gemm_proj_kernel<<<dim3(8, 16, 4), dim3(256), 0, stream>>>(
      xbf, relbf, wt5, qu, qv, kbuf, vtbuf, rbuf, dout, uvec, vvec);
  attn_kernel<<<dim3(64, 32), dim3(256), 0, stream>>>(qu, qv, kbuf, vtbuf, rbuf,
                                                      qseg, kseg, pO, pml);
  combine_kernel<<<dim3(1024), dim3(256), 0, stream>>>(pO, pml, obf);
  gemm_o_kernel<<<dim3(16, 32), dim3(256), 0, stream>>>(obf, wt5 + (4u << 20), dout);
}

// Round 20
// 180.914 us; speedup vs baseline: 1.2001x; 1.2001x over previous
//
#include <hip/hip_runtime.h>
#include <hip/hip_bf16.h>
#include <climits>

// ---------------------------------------------------------------------------
// RelativeMultiHeadAttentionBlock (Transformer-XL style) on MI355X (gfx950)
// B=2, T=C=1024, M=1024, S=2048, H=16, HD=64, F=1024. fp32 in/out, bf16 MFMA.
//
// R19: byte-for-byte revert to R17 (best measured: 180.7us total).
// R18's V-direct experiment regressed (142us attn): occupancy did NOT rise
// when LDS shrank (LDS was not the binding constraint) and V loads
// reintroduced uncovered per-wave L2 latency. Configuration ledger: the
// R15/R17 attn body (4-wave/64-row coop blocks, K+V LDS dbuf staging,
// 4-way split, DPP+exp2 softmax, setprio, interior-skip) has now beaten
// 9 structural variants from every direction -> verified local optimum.
// ---------------------------------------------------------------------------

typedef unsigned short u16;
typedef short bf16x8 __attribute__((ext_vector_type(8)));
typedef float f32x4 __attribute__((ext_vector_type(4)));

__device__ __forceinline__ f32x4 mfma16x16x32(bf16x8 a, bf16x8 b, f32x4 c) {
  return __builtin_amdgcn_mfma_f32_16x16x32_bf16(a, b, c, 0, 0, 0);
}

__device__ __forceinline__ u16 f2bf(float f) {  // RNE via HW cvt
  __hip_bfloat16 h = __float2bfloat16(f);
  return *reinterpret_cast<u16*>(&h);
}

__device__ __forceinline__ float bf2f(u16 x) {
  unsigned u = ((unsigned)x) << 16;
  return __builtin_bit_cast(float, u);
}

__device__ __forceinline__ void gll16(const void* g, void* l) {
  __builtin_amdgcn_global_load_lds(
      (const __attribute__((address_space(1))) void*)g,
      (__attribute__((address_space(3))) void*)l, 16, 0, 0);
}

// DPP 16-lane rotation allreduce (VALU pipe; rows of 16 = our gq groups)
template <int CTRL>
__device__ __forceinline__ float rot16(float x) {
  int i = __builtin_bit_cast(int, x);
  int r = __builtin_amdgcn_update_dpp(i, i, CTRL, 0xF, 0xF, false);
  return __builtin_bit_cast(float, r);
}
__device__ __forceinline__ float dpp_max16(float x) {
  x = fmaxf(x, rot16<0x128>(x));  // ror:8
  x = fmaxf(x, rot16<0x124>(x));  // ror:4
  x = fmaxf(x, rot16<0x122>(x));  // ror:2
  x = fmaxf(x, rot16<0x121>(x));  // ror:1
  return x;
}
__device__ __forceinline__ float dpp_sum16(float x) {
  x += rot16<0x128>(x);
  x += rot16<0x124>(x);
  x += rot16<0x122>(x);
  x += rot16<0x121>(x);
  return x;
}

// --- segment ids ------------------------------------------------------------
__global__ __launch_bounds__(64) void seg_scan_kernel(
    const int* __restrict__ mask, const int* __restrict__ mem_mask,
    const int* __restrict__ cache_mask, int* __restrict__ qseg,
    int* __restrict__ kseg) {
  __shared__ int cs[3072];
  int b = blockIdx.x, lane = threadIdx.x;
  int carry = 0;
  for (int base = 0; base < 3072; base += 64) {
    int idx = base + lane;
    int val;
    if (idx < 1024)      val = mem_mask[b * 1024 + idx];
    else if (idx < 2048) val = cache_mask[b * 1024 + idx - 1024];
    else                 val = mask[b * 1024 + idx - 2048];
    for (int o = 1; o < 64; o <<= 1) {
      int n = __shfl_up(val, o);
      if (lane >= o) val += n;
    }
    val += carry;
    cs[idx] = val;
    carry = __shfl(val, 63);
  }
  __syncthreads();
  int mx = INT_MIN;
  for (int i = lane; i < 2048; i += 64) mx = max(mx, cs[i]);
  for (int o = 1; o < 64; o <<= 1) mx = max(mx, __shfl_xor(mx, o));
  int cs2047 = cs[2047];
  for (int t = lane; t < 1024; t += 64) qseg[b * 1024 + t] = cs[2048 + t] - cs2047 + mx;
  for (int j = lane; j < 2048; j += 64) kseg[b * 2048 + j] = cs[1024 + j];
}

// --- fused prep: [0,4096)=cvt x/rel  [4096,9216)=W^T x5
//                 [9216,11264)=cache_key perm  [11264,13312)=cache_value tr
__global__ __launch_bounds__(256) void prep_kernel(
    const float* __restrict__ x, u16* __restrict__ xbf,
    const float* __restrict__ rel, u16* __restrict__ relbf,
    const float* __restrict__ Wq, const float* __restrict__ Wk,
    const float* __restrict__ Wv, const float* __restrict__ Wr,
    const float* __restrict__ Wo, u16* __restrict__ wt5,
    const float* __restrict__ cache_key, u16* __restrict__ kbuf,
    const float* __restrict__ cache_value, u16* __restrict__ vtbuf) {
  __shared__ float tile[32][33];
  const int bid = blockIdx.x, tid = threadIdx.x;
  if (bid < 4096) {  // cvt x + rel_emb -> bf16
    int q = bid * 256 + tid;
    const float* s;
    u16* d;
    int i;
    if (q < 524288) { s = x; d = xbf; i = q * 4; }
    else            { s = rel; d = relbf; i = (q - 524288) * 4; }
    float4 v = *(const float4*)(s + i);
    d[i + 0] = f2bf(v.x); d[i + 1] = f2bf(v.y);
    d[i + 2] = f2bf(v.z); d[i + 3] = f2bf(v.w);
  } else if (bid < 9216) {  // 5 weight transposes
    int t = bid - 4096;
    int z = t >> 10, rem = t & 1023;
    int bx = rem & 31, byy = rem >> 5;
    const float* src = (z == 0) ? Wq : (z == 1) ? Wk : (z == 2) ? Wv
                       : (z == 3) ? Wr : Wo;
    u16* dst = wt5 + ((size_t)z << 20);
    int tx = tid & 31, ty = tid >> 5;
    int r0 = byy * 32, c0 = bx * 32;
#pragma unroll
    for (int i = 0; i < 32; i += 8)
      tile[ty + i][tx] = src[(size_t)(r0 + ty + i) * 1024 + c0 + tx];
    __syncthreads();
#pragma unroll
    for (int i = 0; i < 32; i += 8)
      dst[(size_t)(c0 + ty + i) * 1024 + r0 + tx] = f2bf(tile[tx][ty + i]);
  } else if (bid < 11264) {  // cache_key (b,t,h,d) -> kbuf[b][h][t][d]
    int i = (bid - 9216) * 256 + tid;  // 524288 quads
    int dq = i & 15, h = (i >> 4) & 15, t = (i >> 8) & 1023, b = i >> 18;
    float4 v = *(const float4*)(cache_key + (size_t)i * 4);
    size_t o = (((size_t)(b * 16 + h)) * 2048 + t) * 64 + dq * 4;
    kbuf[o + 0] = f2bf(v.x); kbuf[o + 1] = f2bf(v.y);
    kbuf[o + 2] = f2bf(v.z); kbuf[o + 3] = f2bf(v.w);
  } else {  // cache_value (b,t,h,d) -> vtbuf[b][h][d][t]
    int t = bid - 11264;  // dims (32, 2, 32): x fastest
    int x0 = t & 31, y0 = (t >> 5) & 1, z0 = t >> 6;
    int bh = z0, b = bh >> 4, h = bh & 15;
    int t0 = x0 * 32, d0 = y0 * 32;
    int tx = tid & 31, ty = tid >> 5;
#pragma unroll
    for (int i = 0; i < 32; i += 8)
      tile[ty + i][tx] =
          cache_value[(((size_t)b * 1024 + t0 + ty + i) * 16 + h) * 64 + d0 + tx];
    __syncthreads();
#pragma unroll
    for (int i = 0; i < 32; i += 8)
      vtbuf[((size_t)bh * 64 + d0 + ty + i) * 2048 + t0 + tx] = f2bf(tile[tx][ty + i]);
  }
}

// --- projection GEMM (modes 0-3): 128x128 tile, BK=64, 4 waves --------------
__global__ __launch_bounds__(256, 2) void gemm_proj_kernel(
    const u16* __restrict__ xbf, const u16* __restrict__ relbf,
    const u16* __restrict__ wt5, u16* __restrict__ qu, u16* __restrict__ qv,
    u16* __restrict__ kbuf, u16* __restrict__ vtbuf, u16* __restrict__ rbuf,
    float* __restrict__ dout, const float* __restrict__ uvec,
    const float* __restrict__ vvec) {
  __shared__ __align__(16) u16 lA[128 * 64];
  __shared__ __align__(16) u16 lB[128 * 64];
  const int mode = (int)blockIdx.z;
  const u16* A = (mode == 3) ? relbf : xbf;
  const u16* Wm = wt5 + (size_t)mode * 1048576;
  const int tid = threadIdx.x;
  const int lane = tid & 63, gq = lane >> 4, cl = lane & 15;
  const int wv = tid >> 6, wm = wv >> 1, wn = wv & 1;
  const int by = blockIdx.y * 128, bx = blockIdx.x * 128;
  const f32x4 fz = {0.f, 0.f, 0.f, 0.f};

  f32x4 acc[4][4];
#pragma unroll
  for (int mi = 0; mi < 4; ++mi)
#pragma unroll
    for (int ni = 0; ni < 4; ++ni) acc[mi][ni] = fz;

  int offs[4];
  const u16 *pA[4], *pB[4];
#pragma unroll
  for (int c = 0; c < 4; ++c) {
    int off = tid * 16 + c * 4096;
    int L = off ^ (((off >> 7) & 7) << 4);
    int rr = off >> 7, ke = (L & 127) >> 1;
    offs[c] = off;
    pA[c] = A + (size_t)(by + rr) * 1024 + ke;
    pB[c] = Wm + (size_t)(bx + rr) * 1024 + ke;
  }

  for (int k0 = 0; k0 < 1024; k0 += 64) {
#pragma unroll
    for (int c = 0; c < 4; ++c) {
      gll16(pA[c] + k0, (char*)lA + offs[c]);
      gll16(pB[c] + k0, (char*)lB + offs[c]);
    }
    __syncthreads();
    bf16x8 af[4][2], bff[4][2];
#pragma unroll
    for (int mi = 0; mi < 4; ++mi)
#pragma unroll
      for (int kb = 0; kb < 2; ++kb) {
        int row = wm * 64 + mi * 16 + cl;
        int byte = row * 128 + kb * 64 + gq * 16;
        byte ^= ((row & 7) << 4);
        af[mi][kb] = *(const bf16x8*)((const char*)lA + byte);
      }
#pragma unroll
    for (int ni = 0; ni < 4; ++ni)
#pragma unroll
      for (int kb = 0; kb < 2; ++kb) {
        int row = wn * 64 + ni * 16 + cl;
        int byte = row * 128 + kb * 64 + gq * 16;
        byte ^= ((row & 7) << 4);
        bff[ni][kb] = *(const bf16x8*)((const char*)lB + byte);
      }
#pragma unroll
    for (int mi = 0; mi < 4; ++mi)
#pragma unroll
      for (int ni = 0; ni < 4; ++ni) {
        acc[mi][ni] = mfma16x16x32(af[mi][0], bff[ni][0], acc[mi][ni]);
        acc[mi][ni] = mfma16x16x32(af[mi][1], bff[ni][1], acc[mi][ni]);
      }
    __syncthreads();
  }

  const float SC = 0.18033688011112042f;  // 0.125 * log2(e)
#pragma unroll
  for (int mi = 0; mi < 4; ++mi)
#pragma unroll
    for (int ni = 0; ni < 4; ++ni) {
      int n = bx + wn * 64 + ni * 16 + cl;
      float ub = 0.f, vb = 0.f;
      if (mode == 0) { ub = uvec[n]; vb = vvec[n]; }
#pragma unroll
      for (int r = 0; r < 4; ++r) {
        int m = by + wm * 64 + mi * 16 + 4 * gq + r;
        float val = acc[mi][ni][r];
        if (mode == 0) {
          qu[(size_t)m * 1024 + n] = f2bf((val + ub) * SC);
          qv[(size_t)m * 1024 + n] = f2bf((val + vb) * SC);
        } else if (mode == 1) {
          dout[2097152 + (size_t)m * 1024 + n] = val;
          kbuf[(((size_t)((m >> 10) * 16 + (n >> 6))) * 2048 + 1024 + (m & 1023)) * 64 +
               (n & 63)] = f2bf(val);
        } else if (mode == 2) {
          dout[4194304 + (size_t)m * 1024 + n] = val;
          vtbuf[(((size_t)((m >> 10) * 16 + (n >> 6))) * 64 + (n & 63)) * 2048 + 1024 +
                (m & 1023)] = f2bf(val);
        } else {
          rbuf[((size_t)(n >> 6) * 2048 + m) * 64 + (n & 63)] = f2bf(val);
        }
      }
    }
}

// --- output GEMM (o @ Wo): 64x64 tile, 4 waves (2x2), 512 blocks ------------
__global__ __launch_bounds__(256, 2) void gemm_o_kernel(
    const u16* __restrict__ obf, const u16* __restrict__ wo,
    float* __restrict__ dout) {
  __shared__ __align__(16) u16 lA[64 * 64];
  __shared__ __align__(16) u16 lB[64 * 64];
  const int tid = threadIdx.x;
  const int lane = tid & 63, gq = lane >> 4, cl = lane & 15;
  const int wv = tid >> 6, wm = wv >> 1, wn = wv & 1;
  const int by = blockIdx.y * 64, bx = blockIdx.x * 64;
  const f32x4 fz = {0.f, 0.f, 0.f, 0.f};

  f32x4 acc[2][2];
#pragma unroll
  for (int a = 0; a < 2; ++a)
#pragma unroll
    for (int bq = 0; bq < 2; ++bq) acc[a][bq] = fz;

  const int off0 = tid * 16, off1 = tid * 16 + 4096;
  const int L0 = off0 ^ (((off0 >> 7) & 7) << 4);
  const int L1 = off1 ^ (((off1 >> 7) & 7) << 4);
  const int rr0 = off0 >> 7, ke0 = (L0 & 127) >> 1;
  const int rr1 = off1 >> 7, ke1 = (L1 & 127) >> 1;
  const u16* pA0 = obf + (size_t)(by + rr0) * 1024 + ke0;
  const u16* pA1 = obf + (size_t)(by + rr1) * 1024 + ke1;
  const u16* pB0 = wo + (size_t)(bx + rr0) * 1024 + ke0;
  const u16* pB1 = wo + (size_t)(bx + rr1) * 1024 + ke1;

  for (int k0 = 0; k0 < 1024; k0 += 64) {
    gll16(pA0 + k0, (char*)lA + off0);
    gll16(pA1 + k0, (char*)lA + off1);
    gll16(pB0 + k0, (char*)lB + off0);
    gll16(pB1 + k0, (char*)lB + off1);
    __syncthreads();
    bf16x8 af[2][2], bff[2][2];
#pragma unroll
    for (int mi = 0; mi < 2; ++mi)
#pragma unroll
      for (int kb = 0; kb < 2; ++kb) {
        int row = wm * 32 + mi * 16 + cl;
        int byte = row * 128 + kb * 64 + gq * 16;
        byte ^= ((row & 7) << 4);
        af[mi][kb] = *(const bf16x8*)((const char*)lA + byte);
      }
#pragma unroll
    for (int ni = 0; ni < 2; ++ni)
#pragma unroll
      for (int kb = 0; kb < 2; ++kb) {
        int row = wn * 32 + ni * 16 + cl;
        int byte = row * 128 + kb * 64 + gq * 16;
        byte ^= ((row & 7) << 4);
        bff[ni][kb] = *(const bf16x8*)((const char*)lB + byte);
      }
#pragma unroll
    for (int mi = 0; mi < 2; ++mi)
#pragma unroll
      for (int ni = 0; ni < 2; ++ni) {
        acc[mi][ni] = mfma16x16x32(af[mi][0], bff[ni][0], acc[mi][ni]);
        acc[mi][ni] = mfma16x16x32(af[mi][1], bff[ni][1], acc[mi][ni]);
      }
    __syncthreads();
  }

#pragma unroll
  for (int mi = 0; mi < 2; ++mi)
#pragma unroll
    for (int ni = 0; ni < 2; ++ni) {
      int n = bx + wn * 32 + ni * 16 + cl;
#pragma unroll
      for (int r = 0; r < 4; ++r) {
        int m = by + wm * 32 + mi * 16 + 4 * gq + r;
        dout[(size_t)m * 1024 + n] = acc[mi][ni][r];
      }
    }
}

// --- flash attention: 4-wave cooperative block (64 q-rows), shared staging --
// grid (64 = qt*4 + chunk, 32 = bh); 4-way key split; LDS 40KB (R15 config).
__global__ __launch_bounds__(256, 2) void attn_kernel(
    const u16* __restrict__ qu, const u16* __restrict__ qv,
    const u16* __restrict__ kbuf, const u16* __restrict__ vtbuf,
    const u16* __restrict__ rbuf, const int* __restrict__ qseg,
    const int* __restrict__ kseg, u16* __restrict__ pO,
    float* __restrict__ pml) {
  __shared__ __align__(16) u16 ldsK[2][64 * 64];  // [buf][s-row][d], swizzled
  __shared__ __align__(16) u16 ldsV[2][64 * 64];  // [buf][d-row][s], swizzled
  __shared__ __align__(16) u16 ldsP[4][16 * 64];  // per-wave P

  const int tid = threadIdx.x, lane = tid & 63;
  const int gq = lane >> 4, cl = lane & 15;
  const int wv = tid >> 6;
  // XCD-locality remap (bijective over 2048): 4 (b,h) per XCD
  int lin = blockIdx.x + 64 * blockIdx.y;
  lin = (lin & 7) * 256 + (lin >> 3);
  const int bh = lin >> 6, xx = lin & 63;
  const int qt = xx >> 2, chunk = xx & 3;
  const int b = bh >> 4, h = bh & 15;
  const int i0b = qt * 64;            // block's first q-row
  const int i0 = i0b + wv * 16;       // this wave's first q-row
  const int tmax = (i0b + 63 + 1024) >> 6;  // block-uniform
  const f32x4 fz = {0.f, 0.f, 0.f, 0.f};

  const u16* rbh = rbuf + (size_t)h * 2048 * 64;
  const int* ksegb = kseg + (size_t)b * 2048;

  // staging: linear LDS dest, pre-swizzled global source (involution)
  const u16* Kbase = kbuf + (size_t)bh * 2048 * 64;
  const u16* Vbase = vtbuf + (size_t)bh * 64 * 2048;
  const int offc0 = tid * 16, offc1 = tid * 16 + 4096;
  const int L0s = offc0 ^ (((offc0 >> 7) & 7) << 4);
  const int L1s = offc1 ^ (((offc1 >> 7) & 7) << 4);
  const u16* kS0 = Kbase + (size_t)(offc0 >> 7) * 64 + ((L0s & 127) >> 1);
  const u16* kS1 = Kbase + (size_t)(offc1 >> 7) * 64 + ((L1s & 127) >> 1);
  const u16* vS0 = Vbase + (size_t)(offc0 >> 7) * 2048 + ((L0s & 127) >> 1);
  const u16* vS1 = Vbase + (size_t)(offc1 >> 7) * 2048 + ((L1s & 127) >> 1);

#define STAGE(T, B)                                                \
  do {                                                             \
    gll16(kS0 + (size_t)(T) * 4096, (char*)ldsK[B] + offc0);       \
    gll16(kS1 + (size_t)(T) * 4096, (char*)ldsK[B] + offc1);       \
    gll16(vS0 + (T) * 64, (char*)ldsV[B] + offc0);                 \
    gll16(vS1 + (T) * 64, (char*)ldsV[B] + offc1);                 \
  } while (0)

  STAGE(chunk, 0);  // prologue prefetch (in flight during Q setup)

  // Q fragments (pre-scaled by 0.125*log2e): row=cl, k=32*kb+8*gq+j
  bf16x8 aU[2], aV[2];
#pragma unroll
  for (int kb = 0; kb < 2; ++kb) {
    size_t off = ((size_t)b * 1024 + i0 + cl) * 1024 + h * 64 + kb * 32 + gq * 8;
    aU[kb] = *(const bf16x8*)(qu + off);
    aV[kb] = *(const bf16x8*)(qv + off);
  }
  // loop-invariant per-row constants
  int qsv[4], srcl[4], athr[4];
  bool sel[4];
#pragma unroll
  for (int r = 0; r < 4; ++r) {
    int ri = 4 * gq + r;
    qsv[r] = qseg[b * 1024 + i0 + ri];
    int lc = cl - ri + 15;  // in [0,30]
    srcl[r] = (gq << 4) | (lc & 15);
    sel[r] = (lc < 16);
    athr[r] = i0 + ri + 1024 - cl;  // causal: j0t+16jt <= athr
  }

  float mrun[4], lrun[4];
  f32x4 oacc[4];
#pragma unroll
  for (int r = 0; r < 4; ++r) { mrun[r] = -1e30f; lrun[r] = 0.f; }
#pragma unroll
  for (int di = 0; di < 4; ++di) oacc[di] = fz;

  __syncthreads();  // staging of first tile complete

  int bufi = 0;
  for (int t = chunk; t <= tmax; t += 4, bufi ^= 1) {
    if (t + 4 <= tmax) STAGE(t + 4, bufi ^ 1);  // overlaps with compute below
    const int j0t = t * 64;
    const int Rb0 = j0t - i0 + 1008;  // 16-aligned band base, >= 0
    const bool interior = (j0t + 63 <= i0 + 1024);  // wave-uniform causal skip
    // ---- per-wave global loads: r bands + kseg, batch-issued + fenced ----
    bf16x8 Rf[5][2];
#pragma unroll
    for (int p = 0; p < 5; ++p) {
      const u16* rp = rbh + (size_t)min(Rb0 + 16 * p + cl, 2047) * 64 + gq * 8;
      Rf[p][0] = *(const bf16x8*)rp;
      Rf[p][1] = *(const bf16x8*)(rp + 32);
    }
    int ksv[4];
#pragma unroll
    for (int jt = 0; jt < 4; ++jt) ksv[jt] = ksegb[j0t + 16 * jt + cl];
    __builtin_amdgcn_sched_barrier(0);

    const char* Kl = (const char*)ldsK[bufi];
    const char* Vl = (const char*)ldsV[bufi];
    // ---- QK^T from LDS ----
    __builtin_amdgcn_s_setprio(1);
    f32x4 xq[4];
#pragma unroll
    for (int jt = 0; jt < 4; ++jt) {
      int row = jt * 16 + cl;
      int sw = (row & 7) << 4;
      bf16x8 k0 = *(const bf16x8*)(Kl + ((row * 128 + gq * 16) ^ sw));
      bf16x8 k1 = *(const bf16x8*)(Kl + ((row * 128 + 64 + gq * 16) ^ sw));
      f32x4 a = mfma16x16x32(aU[0], k0, fz);
      xq[jt] = mfma16x16x32(aU[1], k1, a);
    }
    // ---- bias-band MFMAs (bands shared: bd1[jt] == bd0[jt+1]) ----
    f32x4 bb[5];
#pragma unroll
    for (int p = 0; p < 5; ++p) {
      f32x4 a = mfma16x16x32(aV[0], Rf[p][0], fz);
      bb[p] = mfma16x16x32(aV[1], Rf[p][1], a);
    }
    __builtin_amdgcn_s_setprio(0);
    // ---- diagonal gather: 20 independent bpermutes, batch-issued ----
    float D[5][4];
#pragma unroll
    for (int p = 0; p < 5; ++p)
#pragma unroll
      for (int r = 0; r < 4; ++r) D[p][r] = __shfl(bb[p][r], srcl[r]);
    __builtin_amdgcn_sched_barrier(0);

    // ---- scores + mask (exp2 domain) ----
    float x[4][4];
#pragma unroll
    for (int jt = 0; jt < 4; ++jt)
#pragma unroll
      for (int r = 0; r < 4; ++r) {
        float bdv = sel[r] ? D[jt][r] : D[jt + 1][r];
        bool ok = (interior || (j0t + 16 * jt <= athr[r])) && (ksv[jt] == qsv[r]);
        x[jt][r] = ok ? (xq[jt][r] + bdv) : -1e30f;
      }

    // ---- online softmax (DPP allreduce; exp2) ----
    char* Pm = (char*)ldsP[wv];
    float alf[4];
#pragma unroll
    for (int r = 0; r < 4; ++r) {
      float mx = fmaxf(fmaxf(x[0][r], x[1][r]), fmaxf(x[2][r], x[3][r]));
      mx = dpp_max16(mx);
      float mold = mrun[r];
      float mnew = fmaxf(mold, mx);
      float al = exp2f(mold - mnew);
      float p0 = exp2f(x[0][r] - mnew);
      float p1 = exp2f(x[1][r] - mnew);
      float p2 = exp2f(x[2][r] - mnew);
      float p3 = exp2f(x[3][r] - mnew);
      float s = dpp_sum16(p0 + p1 + p2 + p3);
      mrun[r] = mnew;
      lrun[r] = lrun[r] * al + s;
      alf[r] = al;
      int ri = 4 * gq + r;
      int bbx = (ri & 7) << 4;
      *(u16*)(Pm + ((ri * 128 + cl * 2) ^ bbx)) = f2bf(p0);
      *(u16*)(Pm + ((ri * 128 + (16 + cl) * 2) ^ bbx)) = f2bf(p1);
      *(u16*)(Pm + ((ri * 128 + (32 + cl) * 2) ^ bbx)) = f2bf(p2);
      *(u16*)(Pm + ((ri * 128 + (48 + cl) * 2) ^ bbx)) = f2bf(p3);
    }
    f32x4 av = {alf[0], alf[1], alf[2], alf[3]};
#pragma unroll
    for (int di = 0; di < 4; ++di) oacc[di] *= av;
    // ---- PV: P round-trip (same wave), V from LDS ----
    int psw = (cl & 7) << 4;
    bf16x8 pf0 = *(const bf16x8*)(Pm + ((cl * 128 + gq * 16) ^ psw));
    bf16x8 pf1 = *(const bf16x8*)(Pm + ((cl * 128 + 64 + gq * 16) ^ psw));
    __builtin_amdgcn_s_setprio(1);
#pragma unroll
    for (int di = 0; di < 4; ++di) {
      int row = di * 16 + cl;
      int sw = (row & 7) << 4;
      bf16x8 v0 = *(const bf16x8*)(Vl + ((row * 128 + gq * 16) ^ sw));
      bf16x8 v1 = *(const bf16x8*)(Vl + ((row * 128 + 64 + gq * 16) ^ sw));
      oacc[di] = mfma16x16x32(pf0, v0, oacc[di]);
      oacc[di] = mfma16x16x32(pf1, v1, oacc[di]);
    }
    __builtin_amdgcn_s_setprio(0);
    __syncthreads();  // staging(t+4) landed; protects both buffers
  }
#undef STAGE

  // epilogue: raw partials (no 1/l) + (m,l); non-temporal (protect L2 reads)
#pragma unroll
  for (int r = 0; r < 4; ++r) {
    int iq = i0 + 4 * gq + r;
    size_t rowp = ((size_t)bh * 4 + chunk) * 1024 + iq;
#pragma unroll
    for (int di = 0; di < 4; ++di)
      __builtin_nontemporal_store(f2bf(oacc[di][r]), &pO[rowp * 64 + di * 16 + cl]);
    if (cl == 0) {
      __builtin_nontemporal_store(mrun[r], &pml[rowp * 2]);
      __builtin_nontemporal_store(lrun[r], &pml[rowp * 2 + 1]);
    }
  }
}

// --- split-key combine (4 chunks, exp2 domain) ------------------------------
__global__ __launch_bounds__(256) void combine_kernel(
    const u16* __restrict__ pO, const float* __restrict__ pml,
    u16* __restrict__ obf) {
  int gid = blockIdx.x * 256 + threadIdx.x;  // 262144
  int d8 = (gid & 7) * 8;
  int row = gid >> 3;  // bh*1024 + iq
  int bh = row >> 10, iq = row & 1023;
  int b = bh >> 4, h = bh & 15;
  size_t rbase = (size_t)bh * 4 * 1024 + iq;
  float m[4], l[4], w[4];
  float ms = -1e30f;
#pragma unroll
  for (int c = 0; c < 4; ++c) {
    m[c] = pml[(rbase + c * 1024) * 2];
    l[c] = pml[(rbase + c * 1024) * 2 + 1];
    ms = fmaxf(ms, m[c]);
  }
  float den = 0.f;
#pragma unroll
  for (int c = 0; c < 4; ++c) { w[c] = exp2f(m[c] - ms); den += l[c] * w[c]; }
  float inv = 1.0f / fmaxf(den, 1e-30f);
  float acc[8] = {0, 0, 0, 0, 0, 0, 0, 0};
#pragma unroll
  for (int c = 0; c < 4; ++c) {
    bf16x8 a = *(const bf16x8*)(pO + (rbase + c * 1024) * 64 + d8);
#pragma unroll
    for (int j = 0; j < 8; ++j) acc[j] += bf2f((u16)a[j]) * w[c];
  }
  bf16x8 o;
#pragma unroll
  for (int j = 0; j < 8; ++j) o[j] = (short)f2bf(acc[j] * inv);
  *(bf16x8*)(obf + ((size_t)b * 1024 + iq) * 1024 + h * 64 + d8) = o;
}

// ---------------------------------------------------------------------------
extern "C" void kernel_launch(void* const* d_in, const int* in_sizes, int n_in,
                              void* d_out, int out_size, void* d_ws, size_t ws_size,
                              hipStream_t stream) {
  (void)in_sizes; (void)n_in; (void)out_size; (void)ws_size;
  const float* x           = (const float*)d_in[0];
  const int*   mask        = (const int*)d_in[1];
  const int*   mem_mask    = (const int*)d_in[3];
  const float* cache_key   = (const float*)d_in[4];
  const float* cache_value = (const float*)d_in[5];
  const int*   cache_mask  = (const int*)d_in[6];
  const float* rel_emb     = (const float*)d_in[7];
  const float* Wq          = (const float*)d_in[8];
  const float* Wk          = (const float*)d_in[9];
  const float* Wv          = (const float*)d_in[10];
  const float* Wr          = (const float*)d_in[11];
  const float* uvec        = (const float*)d_in[12];
  const float* vvec        = (const float*)d_in[13];
  const float* Wo          = (const float*)d_in[14];
  float* dout = (float*)d_out;

  char* W = (char*)d_ws;  // ~51.1 MB of workspace used
  u16* xbf   = (u16*)(W + (0u << 20));   // dead after projection GEMMs
  u16* relbf = (u16*)(W + (4u << 20));   // dead after projection GEMMs
  u16* pO    = (u16*)(W + (0u << 20));   // 16MB: overlays xbf,relbf,wt5[0..3]
  u16* wt5   = (u16*)(W + (8u << 20));   // q,k,v,r dead by attn; o at +8MB
  u16* kbuf  = (u16*)(W + (18u << 20));
  u16* vtbuf = (u16*)(W + (26u << 20));
  u16* rbuf  = (u16*)(W + (34u << 20));
  u16* qu    = (u16*)(W + (38u << 20));
  u16* qv    = (u16*)(W + (42u << 20));
  u16* obf   = (u16*)(W + (46u << 20));
  int* qseg  = (int*)(W + (50u << 20));
  int* kseg  = (int*)(W + (50u << 20) + 8192);
  float* pml = (float*)(W + (50u << 20) + 32768);

  seg_scan_kernel<<<dim3(2), dim3(64), 0, stream>>>(mask, mem_mask, cache_mask, qseg, kseg);
  prep_kernel<<<dim3(13312), dim3(256), 0, stream>>>(
      x, xbf, rel_emb, relbf, Wq, Wk, Wv, Wr, Wo, wt5, cache_key, kbuf,
      cache_value, vtbuf);
  gemm_proj_kernel<<<dim3(8, 16, 4), dim3(256), 0, stream>>>(
      xbf, relbf, wt5, qu, qv, kbuf, vtbuf, rbuf, dout, uvec, vvec);
  attn_kernel<<<dim3(64, 32), dim3(256), 0, stream>>>(qu, qv, kbuf, vtbuf, rbuf,
                                                      qseg, kseg, pO, pml);
  combine_kernel<<<dim3(1024), dim3(256), 0, stream>>>(pO, pml, obf);
  gemm_o_kernel<<<dim3(16, 32), dim3(256), 0, stream>>>(obf, wt5 + (4u << 20), dout);
}

// Round 21
// 177.887 us; speedup vs baseline: 1.2205x; 1.0170x over previous
//
#include <hip/hip_runtime.h>
#include <hip/hip_bf16.h>
#include <climits>

// ---------------------------------------------------------------------------
// RelativeMultiHeadAttentionBlock (Transformer-XL style) on MI355X (gfx950)
// B=2, T=C=1024, M=1024, S=2048, H=16, HD=64, F=1024. fp32 in/out, bf16 MFMA.
//
// R20: final consolidation on the verified R17/R19 configuration (180.7us).
// seg_scan (2-block serial head dispatch) folded into prep_kernel as blocks
// [13312,13314): its ~5us + one launch overhead now hide under prep's
// HBM-bound streaming. attn/gemm bodies byte-identical to R19.
//
// Config ledger (20 rounds): attn = 4-wave/64-row coop blocks, K+V LDS dbuf
// via global_load_lds w/ XOR-swizzle, 4-way key split, DPP+exp2 softmax,
// setprio, interior-skip -> beat 9 structural variants. gemm_proj = 128^2
// m97-structure. prep = fused single pass (HBM-bound).
// ---------------------------------------------------------------------------

typedef unsigned short u16;
typedef short bf16x8 __attribute__((ext_vector_type(8)));
typedef float f32x4 __attribute__((ext_vector_type(4)));

__device__ __forceinline__ f32x4 mfma16x16x32(bf16x8 a, bf16x8 b, f32x4 c) {
  return __builtin_amdgcn_mfma_f32_16x16x32_bf16(a, b, c, 0, 0, 0);
}

__device__ __forceinline__ u16 f2bf(float f) {  // RNE via HW cvt
  __hip_bfloat16 h = __float2bfloat16(f);
  return *reinterpret_cast<u16*>(&h);
}

__device__ __forceinline__ float bf2f(u16 x) {
  unsigned u = ((unsigned)x) << 16;
  return __builtin_bit_cast(float, u);
}

__device__ __forceinline__ void gll16(const void* g, void* l) {
  __builtin_amdgcn_global_load_lds(
      (const __attribute__((address_space(1))) void*)g,
      (__attribute__((address_space(3))) void*)l, 16, 0, 0);
}

// DPP 16-lane rotation allreduce (VALU pipe; rows of 16 = our gq groups)
template <int CTRL>
__device__ __forceinline__ float rot16(float x) {
  int i = __builtin_bit_cast(int, x);
  int r = __builtin_amdgcn_update_dpp(i, i, CTRL, 0xF, 0xF, false);
  return __builtin_bit_cast(float, r);
}
__device__ __forceinline__ float dpp_max16(float x) {
  x = fmaxf(x, rot16<0x128>(x));  // ror:8
  x = fmaxf(x, rot16<0x124>(x));  // ror:4
  x = fmaxf(x, rot16<0x122>(x));  // ror:2
  x = fmaxf(x, rot16<0x121>(x));  // ror:1
  return x;
}
__device__ __forceinline__ float dpp_sum16(float x) {
  x += rot16<0x128>(x);
  x += rot16<0x124>(x);
  x += rot16<0x122>(x);
  x += rot16<0x121>(x);
  return x;
}

// --- fused prep: [0,4096)=cvt x/rel  [4096,9216)=W^T x5
//                 [9216,11264)=cache_key perm  [11264,13312)=cache_value tr
//                 [13312,13314)=segment-id scan (batch = bid-13312)
__global__ __launch_bounds__(256) void prep_kernel(
    const float* __restrict__ x, u16* __restrict__ xbf,
    const float* __restrict__ rel, u16* __restrict__ relbf,
    const float* __restrict__ Wq, const float* __restrict__ Wk,
    const float* __restrict__ Wv, const float* __restrict__ Wr,
    const float* __restrict__ Wo, u16* __restrict__ wt5,
    const float* __restrict__ cache_key, u16* __restrict__ kbuf,
    const float* __restrict__ cache_value, u16* __restrict__ vtbuf,
    const int* __restrict__ mask, const int* __restrict__ mem_mask,
    const int* __restrict__ cache_mask, int* __restrict__ qseg,
    int* __restrict__ kseg) {
  __shared__ float tile[32][33];
  __shared__ int cs[3072];
  const int bid = blockIdx.x, tid = threadIdx.x;
  if (bid < 4096) {  // cvt x + rel_emb -> bf16
    int q = bid * 256 + tid;
    const float* s;
    u16* d;
    int i;
    if (q < 524288) { s = x; d = xbf; i = q * 4; }
    else            { s = rel; d = relbf; i = (q - 524288) * 4; }
    float4 v = *(const float4*)(s + i);
    d[i + 0] = f2bf(v.x); d[i + 1] = f2bf(v.y);
    d[i + 2] = f2bf(v.z); d[i + 3] = f2bf(v.w);
  } else if (bid < 9216) {  // 5 weight transposes
    int t = bid - 4096;
    int z = t >> 10, rem = t & 1023;
    int bx = rem & 31, byy = rem >> 5;
    const float* src = (z == 0) ? Wq : (z == 1) ? Wk : (z == 2) ? Wv
                       : (z == 3) ? Wr : Wo;
    u16* dst = wt5 + ((size_t)z << 20);
    int tx = tid & 31, ty = tid >> 5;
    int r0 = byy * 32, c0 = bx * 32;
#pragma unroll
    for (int i = 0; i < 32; i += 8)
      tile[ty + i][tx] = src[(size_t)(r0 + ty + i) * 1024 + c0 + tx];
    __syncthreads();
#pragma unroll
    for (int i = 0; i < 32; i += 8)
      dst[(size_t)(c0 + ty + i) * 1024 + r0 + tx] = f2bf(tile[tx][ty + i]);
  } else if (bid < 11264) {  // cache_key (b,t,h,d) -> kbuf[b][h][t][d]
    int i = (bid - 9216) * 256 + tid;  // 524288 quads
    int dq = i & 15, h = (i >> 4) & 15, t = (i >> 8) & 1023, b = i >> 18;
    float4 v = *(const float4*)(cache_key + (size_t)i * 4);
    size_t o = (((size_t)(b * 16 + h)) * 2048 + t) * 64 + dq * 4;
    kbuf[o + 0] = f2bf(v.x); kbuf[o + 1] = f2bf(v.y);
    kbuf[o + 2] = f2bf(v.z); kbuf[o + 3] = f2bf(v.w);
  } else if (bid < 13312) {  // cache_value (b,t,h,d) -> vtbuf[b][h][d][t]
    int t = bid - 11264;  // dims (32, 2, 32): x fastest
    int x0 = t & 31, y0 = (t >> 5) & 1, z0 = t >> 6;
    int bh = z0, b = bh >> 4, h = bh & 15;
    int t0 = x0 * 32, d0 = y0 * 32;
    int tx = tid & 31, ty = tid >> 5;
#pragma unroll
    for (int i = 0; i < 32; i += 8)
      tile[ty + i][tx] =
          cache_value[(((size_t)b * 1024 + t0 + ty + i) * 16 + h) * 64 + d0 + tx];
    __syncthreads();
#pragma unroll
    for (int i = 0; i < 32; i += 8)
      vtbuf[((size_t)bh * 64 + d0 + ty + i) * 2048 + t0 + tx] = f2bf(tile[tx][ty + i]);
  } else {  // segment-id cumsum scan for batch b (wave 0 only; others barrier)
    int b = bid - 13312;
    int lane = tid & 63;
    if (tid < 64) {
      int carry = 0;
      for (int base = 0; base < 3072; base += 64) {
        int idx = base + lane;
        int val;
        if (idx < 1024)      val = mem_mask[b * 1024 + idx];
        else if (idx < 2048) val = cache_mask[b * 1024 + idx - 1024];
        else                 val = mask[b * 1024 + idx - 2048];
        for (int o = 1; o < 64; o <<= 1) {
          int n = __shfl_up(val, o);
          if (lane >= o) val += n;
        }
        val += carry;
        cs[idx] = val;
        carry = __shfl(val, 63);
      }
    }
    __syncthreads();
    if (tid < 64) {
      int mx = INT_MIN;
      for (int i = lane; i < 2048; i += 64) mx = max(mx, cs[i]);
      for (int o = 1; o < 64; o <<= 1) mx = max(mx, __shfl_xor(mx, o));
      int cs2047 = cs[2047];
      for (int t = lane; t < 1024; t += 64)
        qseg[b * 1024 + t] = cs[2048 + t] - cs2047 + mx;
      for (int j = lane; j < 2048; j += 64) kseg[b * 2048 + j] = cs[1024 + j];
    }
  }
}

// --- projection GEMM (modes 0-3): 128x128 tile, BK=64, 4 waves --------------
__global__ __launch_bounds__(256, 2) void gemm_proj_kernel(
    const u16* __restrict__ xbf, const u16* __restrict__ relbf,
    const u16* __restrict__ wt5, u16* __restrict__ qu, u16* __restrict__ qv,
    u16* __restrict__ kbuf, u16* __restrict__ vtbuf, u16* __restrict__ rbuf,
    float* __restrict__ dout, const float* __restrict__ uvec,
    const float* __restrict__ vvec) {
  __shared__ __align__(16) u16 lA[128 * 64];
  __shared__ __align__(16) u16 lB[128 * 64];
  const int mode = (int)blockIdx.z;
  const u16* A = (mode == 3) ? relbf : xbf;
  const u16* Wm = wt5 + (size_t)mode * 1048576;
  const int tid = threadIdx.x;
  const int lane = tid & 63, gq = lane >> 4, cl = lane & 15;
  const int wv = tid >> 6, wm = wv >> 1, wn = wv & 1;
  const int by = blockIdx.y * 128, bx = blockIdx.x * 128;
  const f32x4 fz = {0.f, 0.f, 0.f, 0.f};

  f32x4 acc[4][4];
#pragma unroll
  for (int mi = 0; mi < 4; ++mi)
#pragma unroll
    for (int ni = 0; ni < 4; ++ni) acc[mi][ni] = fz;

  int offs[4];
  const u16 *pA[4], *pB[4];
#pragma unroll
  for (int c = 0; c < 4; ++c) {
    int off = tid * 16 + c * 4096;
    int L = off ^ (((off >> 7) & 7) << 4);
    int rr = off >> 7, ke = (L & 127) >> 1;
    offs[c] = off;
    pA[c] = A + (size_t)(by + rr) * 1024 + ke;
    pB[c] = Wm + (size_t)(bx + rr) * 1024 + ke;
  }

  for (int k0 = 0; k0 < 1024; k0 += 64) {
#pragma unroll
    for (int c = 0; c < 4; ++c) {
      gll16(pA[c] + k0, (char*)lA + offs[c]);
      gll16(pB[c] + k0, (char*)lB + offs[c]);
    }
    __syncthreads();
    bf16x8 af[4][2], bff[4][2];
#pragma unroll
    for (int mi = 0; mi < 4; ++mi)
#pragma unroll
      for (int kb = 0; kb < 2; ++kb) {
        int row = wm * 64 + mi * 16 + cl;
        int byte = row * 128 + kb * 64 + gq * 16;
        byte ^= ((row & 7) << 4);
        af[mi][kb] = *(const bf16x8*)((const char*)lA + byte);
      }
#pragma unroll
    for (int ni = 0; ni < 4; ++ni)
#pragma unroll
      for (int kb = 0; kb < 2; ++kb) {
        int row = wn * 64 + ni * 16 + cl;
        int byte = row * 128 + kb * 64 + gq * 16;
        byte ^= ((row & 7) << 4);
        bff[ni][kb] = *(const bf16x8*)((const char*)lB + byte);
      }
#pragma unroll
    for (int mi = 0; mi < 4; ++mi)
#pragma unroll
      for (int ni = 0; ni < 4; ++ni) {
        acc[mi][ni] = mfma16x16x32(af[mi][0], bff[ni][0], acc[mi][ni]);
        acc[mi][ni] = mfma16x16x32(af[mi][1], bff[ni][1], acc[mi][ni]);
      }
    __syncthreads();
  }

  const float SC = 0.18033688011112042f;  // 0.125 * log2(e)
#pragma unroll
  for (int mi = 0; mi < 4; ++mi)
#pragma unroll
    for (int ni = 0; ni < 4; ++ni) {
      int n = bx + wn * 64 + ni * 16 + cl;
      float ub = 0.f, vb = 0.f;
      if (mode == 0) { ub = uvec[n]; vb = vvec[n]; }
#pragma unroll
      for (int r = 0; r < 4; ++r) {
        int m = by + wm * 64 + mi * 16 + 4 * gq + r;
        float val = acc[mi][ni][r];
        if (mode == 0) {
          qu[(size_t)m * 1024 + n] = f2bf((val + ub) * SC);
          qv[(size_t)m * 1024 + n] = f2bf((val + vb) * SC);
        } else if (mode == 1) {
          dout[2097152 + (size_t)m * 1024 + n] = val;
          kbuf[(((size_t)((m >> 10) * 16 + (n >> 6))) * 2048 + 1024 + (m & 1023)) * 64 +
               (n & 63)] = f2bf(val);
        } else if (mode == 2) {
          dout[4194304 + (size_t)m * 1024 + n] = val;
          vtbuf[(((size_t)((m >> 10) * 16 + (n >> 6))) * 64 + (n & 63)) * 2048 + 1024 +
                (m & 1023)] = f2bf(val);
        } else {
          rbuf[((size_t)(n >> 6) * 2048 + m) * 64 + (n & 63)] = f2bf(val);
        }
      }
    }
}

// --- output GEMM (o @ Wo): 64x64 tile, 4 waves (2x2), 512 blocks ------------
__global__ __launch_bounds__(256, 2) void gemm_o_kernel(
    const u16* __restrict__ obf, const u16* __restrict__ wo,
    float* __restrict__ dout) {
  __shared__ __align__(16) u16 lA[64 * 64];
  __shared__ __align__(16) u16 lB[64 * 64];
  const int tid = threadIdx.x;
  const int lane = tid & 63, gq = lane >> 4, cl = lane & 15;
  const int wv = tid >> 6, wm = wv >> 1, wn = wv & 1;
  const int by = blockIdx.y * 64, bx = blockIdx.x * 64;
  const f32x4 fz = {0.f, 0.f, 0.f, 0.f};

  f32x4 acc[2][2];
#pragma unroll
  for (int a = 0; a < 2; ++a)
#pragma unroll
    for (int bq = 0; bq < 2; ++bq) acc[a][bq] = fz;

  const int off0 = tid * 16, off1 = tid * 16 + 4096;
  const int L0 = off0 ^ (((off0 >> 7) & 7) << 4);
  const int L1 = off1 ^ (((off1 >> 7) & 7) << 4);
  const int rr0 = off0 >> 7, ke0 = (L0 & 127) >> 1;
  const int rr1 = off1 >> 7, ke1 = (L1 & 127) >> 1;
  const u16* pA0 = obf + (size_t)(by + rr0) * 1024 + ke0;
  const u16* pA1 = obf + (size_t)(by + rr1) * 1024 + ke1;
  const u16* pB0 = wo + (size_t)(bx + rr0) * 1024 + ke0;
  const u16* pB1 = wo + (size_t)(bx + rr1) * 1024 + ke1;

  for (int k0 = 0; k0 < 1024; k0 += 64) {
    gll16(pA0 + k0, (char*)lA + off0);
    gll16(pA1 + k0, (char*)lA + off1);
    gll16(pB0 + k0, (char*)lB + off0);
    gll16(pB1 + k0, (char*)lB + off1);
    __syncthreads();
    bf16x8 af[2][2], bff[2][2];
#pragma unroll
    for (int mi = 0; mi < 2; ++mi)
#pragma unroll
      for (int kb = 0; kb < 2; ++kb) {
        int row = wm * 32 + mi * 16 + cl;
        int byte = row * 128 + kb * 64 + gq * 16;
        byte ^= ((row & 7) << 4);
        af[mi][kb] = *(const bf16x8*)((const char*)lA + byte);
      }
#pragma unroll
    for (int ni = 0; ni < 2; ++ni)
#pragma unroll
      for (int kb = 0; kb < 2; ++kb) {
        int row = wn * 32 + ni * 16 + cl;
        int byte = row * 128 + kb * 64 + gq * 16;
        byte ^= ((row & 7) << 4);
        bff[ni][kb] = *(const bf16x8*)((const char*)lB + byte);
      }
#pragma unroll
    for (int mi = 0; mi < 2; ++mi)
#pragma unroll
      for (int ni = 0; ni < 2; ++ni) {
        acc[mi][ni] = mfma16x16x32(af[mi][0], bff[ni][0], acc[mi][ni]);
        acc[mi][ni] = mfma16x16x32(af[mi][1], bff[ni][1], acc[mi][ni]);
      }
    __syncthreads();
  }

#pragma unroll
  for (int mi = 0; mi < 2; ++mi)
#pragma unroll
    for (int ni = 0; ni < 2; ++ni) {
      int n = bx + wn * 32 + ni * 16 + cl;
#pragma unroll
      for (int r = 0; r < 4; ++r) {
        int m = by + wm * 32 + mi * 16 + 4 * gq + r;
        dout[(size_t)m * 1024 + n] = acc[mi][ni][r];
      }
    }
}

// --- flash attention: 4-wave cooperative block (64 q-rows), shared staging --
// grid (64 = qt*4 + chunk, 32 = bh); 4-way key split; LDS 40KB (R15 config).
__global__ __launch_bounds__(256, 2) void attn_kernel(
    const u16* __restrict__ qu, const u16* __restrict__ qv,
    const u16* __restrict__ kbuf, const u16* __restrict__ vtbuf,
    const u16* __restrict__ rbuf, const int* __restrict__ qseg,
    const int* __restrict__ kseg, u16* __restrict__ pO,
    float* __restrict__ pml) {
  __shared__ __align__(16) u16 ldsK[2][64 * 64];  // [buf][s-row][d], swizzled
  __shared__ __align__(16) u16 ldsV[2][64 * 64];  // [buf][d-row][s], swizzled
  __shared__ __align__(16) u16 ldsP[4][16 * 64];  // per-wave P

  const int tid = threadIdx.x, lane = tid & 63;
  const int gq = lane >> 4, cl = lane & 15;
  const int wv = tid >> 6;
  // XCD-locality remap (bijective over 2048): 4 (b,h) per XCD
  int lin = blockIdx.x + 64 * blockIdx.y;
  lin = (lin & 7) * 256 + (lin >> 3);
  const int bh = lin >> 6, xx = lin & 63;
  const int qt = xx >> 2, chunk = xx & 3;
  const int b = bh >> 4, h = bh & 15;
  const int i0b = qt * 64;            // block's first q-row
  const int i0 = i0b + wv * 16;       // this wave's first q-row
  const int tmax = (i0b + 63 + 1024) >> 6;  // block-uniform
  const f32x4 fz = {0.f, 0.f, 0.f, 0.f};

  const u16* rbh = rbuf + (size_t)h * 2048 * 64;
  const int* ksegb = kseg + (size_t)b * 2048;

  // staging: linear LDS dest, pre-swizzled global source (involution)
  const u16* Kbase = kbuf + (size_t)bh * 2048 * 64;
  const u16* Vbase = vtbuf + (size_t)bh * 64 * 2048;
  const int offc0 = tid * 16, offc1 = tid * 16 + 4096;
  const int L0s = offc0 ^ (((offc0 >> 7) & 7) << 4);
  const int L1s = offc1 ^ (((offc1 >> 7) & 7) << 4);
  const u16* kS0 = Kbase + (size_t)(offc0 >> 7) * 64 + ((L0s & 127) >> 1);
  const u16* kS1 = Kbase + (size_t)(offc1 >> 7) * 64 + ((L1s & 127) >> 1);
  const u16* vS0 = Vbase + (size_t)(offc0 >> 7) * 2048 + ((L0s & 127) >> 1);
  const u16* vS1 = Vbase + (size_t)(offc1 >> 7) * 2048 + ((L1s & 127) >> 1);

#define STAGE(T, B)                                                \
  do {                                                             \
    gll16(kS0 + (size_t)(T) * 4096, (char*)ldsK[B] + offc0);       \
    gll16(kS1 + (size_t)(T) * 4096, (char*)ldsK[B] + offc1);       \
    gll16(vS0 + (T) * 64, (char*)ldsV[B] + offc0);                 \
    gll16(vS1 + (T) * 64, (char*)ldsV[B] + offc1);                 \
  } while (0)

  STAGE(chunk, 0);  // prologue prefetch (in flight during Q setup)

  // Q fragments (pre-scaled by 0.125*log2e): row=cl, k=32*kb+8*gq+j
  bf16x8 aU[2], aV[2];
#pragma unroll
  for (int kb = 0; kb < 2; ++kb) {
    size_t off = ((size_t)b * 1024 + i0 + cl) * 1024 + h * 64 + kb * 32 + gq * 8;
    aU[kb] = *(const bf16x8*)(qu + off);
    aV[kb] = *(const bf16x8*)(qv + off);
  }
  // loop-invariant per-row constants
  int qsv[4], srcl[4], athr[4];
  bool sel[4];
#pragma unroll
  for (int r = 0; r < 4; ++r) {
    int ri = 4 * gq + r;
    qsv[r] = qseg[b * 1024 + i0 + ri];
    int lc = cl - ri + 15;  // in [0,30]
    srcl[r] = (gq << 4) | (lc & 15);
    sel[r] = (lc < 16);
    athr[r] = i0 + ri + 1024 - cl;  // causal: j0t+16jt <= athr
  }

  float mrun[4], lrun[4];
  f32x4 oacc[4];
#pragma unroll
  for (int r = 0; r < 4; ++r) { mrun[r] = -1e30f; lrun[r] = 0.f; }
#pragma unroll
  for (int di = 0; di < 4; ++di) oacc[di] = fz;

  __syncthreads();  // staging of first tile complete

  int bufi = 0;
  for (int t = chunk; t <= tmax; t += 4, bufi ^= 1) {
    if (t + 4 <= tmax) STAGE(t + 4, bufi ^ 1);  // overlaps with compute below
    const int j0t = t * 64;
    const int Rb0 = j0t - i0 + 1008;  // 16-aligned band base, >= 0
    const bool interior = (j0t + 63 <= i0 + 1024);  // wave-uniform causal skip
    // ---- per-wave global loads: r bands + kseg, batch-issued + fenced ----
    bf16x8 Rf[5][2];
#pragma unroll
    for (int p = 0; p < 5; ++p) {
      const u16* rp = rbh + (size_t)min(Rb0 + 16 * p + cl, 2047) * 64 + gq * 8;
      Rf[p][0] = *(const bf16x8*)rp;
      Rf[p][1] = *(const bf16x8*)(rp + 32);
    }
    int ksv[4];
#pragma unroll
    for (int jt = 0; jt < 4; ++jt) ksv[jt] = ksegb[j0t + 16 * jt + cl];
    __builtin_amdgcn_sched_barrier(0);

    const char* Kl = (const char*)ldsK[bufi];
    const char* Vl = (const char*)ldsV[bufi];
    // ---- QK^T from LDS ----
    __builtin_amdgcn_s_setprio(1);
    f32x4 xq[4];
#pragma unroll
    for (int jt = 0; jt < 4; ++jt) {
      int row = jt * 16 + cl;
      int sw = (row & 7) << 4;
      bf16x8 k0 = *(const bf16x8*)(Kl + ((row * 128 + gq * 16) ^ sw));
      bf16x8 k1 = *(const bf16x8*)(Kl + ((row * 128 + 64 + gq * 16) ^ sw));
      f32x4 a = mfma16x16x32(aU[0], k0, fz);
      xq[jt] = mfma16x16x32(aU[1], k1, a);
    }
    // ---- bias-band MFMAs (bands shared: bd1[jt] == bd0[jt+1]) ----
    f32x4 bb[5];
#pragma unroll
    for (int p = 0; p < 5; ++p) {
      f32x4 a = mfma16x16x32(aV[0], Rf[p][0], fz);
      bb[p] = mfma16x16x32(aV[1], Rf[p][1], a);
    }
    __builtin_amdgcn_s_setprio(0);
    // ---- diagonal gather: 20 independent bpermutes, batch-issued ----
    float D[5][4];
#pragma unroll
    for (int p = 0; p < 5; ++p)
#pragma unroll
      for (int r = 0; r < 4; ++r) D[p][r] = __shfl(bb[p][r], srcl[r]);
    __builtin_amdgcn_sched_barrier(0);

    // ---- scores + mask (exp2 domain) ----
    float x[4][4];
#pragma unroll
    for (int jt = 0; jt < 4; ++jt)
#pragma unroll
      for (int r = 0; r < 4; ++r) {
        float bdv = sel[r] ? D[jt][r] : D[jt + 1][r];
        bool ok = (interior || (j0t + 16 * jt <= athr[r])) && (ksv[jt] == qsv[r]);
        x[jt][r] = ok ? (xq[jt][r] + bdv) : -1e30f;
      }

    // ---- online softmax (DPP allreduce; exp2) ----
    char* Pm = (char*)ldsP[wv];
    float alf[4];
#pragma unroll
    for (int r = 0; r < 4; ++r) {
      float mx = fmaxf(fmaxf(x[0][r], x[1][r]), fmaxf(x[2][r], x[3][r]));
      mx = dpp_max16(mx);
      float mold = mrun[r];
      float mnew = fmaxf(mold, mx);
      float al = exp2f(mold - mnew);
      float p0 = exp2f(x[0][r] - mnew);
      float p1 = exp2f(x[1][r] - mnew);
      float p2 = exp2f(x[2][r] - mnew);
      float p3 = exp2f(x[3][r] - mnew);
      float s = dpp_sum16(p0 + p1 + p2 + p3);
      mrun[r] = mnew;
      lrun[r] = lrun[r] * al + s;
      alf[r] = al;
      int ri = 4 * gq + r;
      int bbx = (ri & 7) << 4;
      *(u16*)(Pm + ((ri * 128 + cl * 2) ^ bbx)) = f2bf(p0);
      *(u16*)(Pm + ((ri * 128 + (16 + cl) * 2) ^ bbx)) = f2bf(p1);
      *(u16*)(Pm + ((ri * 128 + (32 + cl) * 2) ^ bbx)) = f2bf(p2);
      *(u16*)(Pm + ((ri * 128 + (48 + cl) * 2) ^ bbx)) = f2bf(p3);
    }
    f32x4 av = {alf[0], alf[1], alf[2], alf[3]};
#pragma unroll
    for (int di = 0; di < 4; ++di) oacc[di] *= av;
    // ---- PV: P round-trip (same wave), V from LDS ----
    int psw = (cl & 7) << 4;
    bf16x8 pf0 = *(const bf16x8*)(Pm + ((cl * 128 + gq * 16) ^ psw));
    bf16x8 pf1 = *(const bf16x8*)(Pm + ((cl * 128 + 64 + gq * 16) ^ psw));
    __builtin_amdgcn_s_setprio(1);
#pragma unroll
    for (int di = 0; di < 4; ++di) {
      int row = di * 16 + cl;
      int sw = (row & 7) << 4;
      bf16x8 v0 = *(const bf16x8*)(Vl + ((row * 128 + gq * 16) ^ sw));
      bf16x8 v1 = *(const bf16x8*)(Vl + ((row * 128 + 64 + gq * 16) ^ sw));
      oacc[di] = mfma16x16x32(pf0, v0, oacc[di]);
      oacc[di] = mfma16x16x32(pf1, v1, oacc[di]);
    }
    __builtin_amdgcn_s_setprio(0);
    __syncthreads();  // staging(t+4) landed; protects both buffers
  }
#undef STAGE

  // epilogue: raw partials (no 1/l) + (m,l); non-temporal (protect L2 reads)
#pragma unroll
  for (int r = 0; r < 4; ++r) {
    int iq = i0 + 4 * gq + r;
    size_t rowp = ((size_t)bh * 4 + chunk) * 1024 + iq;
#pragma unroll
    for (int di = 0; di < 4; ++di)
      __builtin_nontemporal_store(f2bf(oacc[di][r]), &pO[rowp * 64 + di * 16 + cl]);
    if (cl == 0) {
      __builtin_nontemporal_store(mrun[r], &pml[rowp * 2]);
      __builtin_nontemporal_store(lrun[r], &pml[rowp * 2 + 1]);
    }
  }
}

// --- split-key combine (4 chunks, exp2 domain) ------------------------------
__global__ __launch_bounds__(256) void combine_kernel(
    const u16* __restrict__ pO, const float* __restrict__ pml,
    u16* __restrict__ obf) {
  int gid = blockIdx.x * 256 + threadIdx.x;  // 262144
  int d8 = (gid & 7) * 8;
  int row = gid >> 3;  // bh*1024 + iq
  int bh = row >> 10, iq = row & 1023;
  int b = bh >> 4, h = bh & 15;
  size_t rbase = (size_t)bh * 4 * 1024 + iq;
  float m[4], l[4], w[4];
  float ms = -1e30f;
#pragma unroll
  for (int c = 0; c < 4; ++c) {
    m[c] = pml[(rbase + c * 1024) * 2];
    l[c] = pml[(rbase + c * 1024) * 2 + 1];
    ms = fmaxf(ms, m[c]);
  }
  float den = 0.f;
#pragma unroll
  for (int c = 0; c < 4; ++c) { w[c] = exp2f(m[c] - ms); den += l[c] * w[c]; }
  float inv = 1.0f / fmaxf(den, 1e-30f);
  float acc[8] = {0, 0, 0, 0, 0, 0, 0, 0};
#pragma unroll
  for (int c = 0; c < 4; ++c) {
    bf16x8 a = *(const bf16x8*)(pO + (rbase + c * 1024) * 64 + d8);
#pragma unroll
    for (int j = 0; j < 8; ++j) acc[j] += bf2f((u16)a[j]) * w[c];
  }
  bf16x8 o;
#pragma unroll
  for (int j = 0; j < 8; ++j) o[j] = (short)f2bf(acc[j] * inv);
  *(bf16x8*)(obf + ((size_t)b * 1024 + iq) * 1024 + h * 64 + d8) = o;
}

// ---------------------------------------------------------------------------
extern "C" void kernel_launch(void* const* d_in, const int* in_sizes, int n_in,
                              void* d_out, int out_size, void* d_ws, size_t ws_size,
                              hipStream_t stream) {
  (void)in_sizes; (void)n_in; (void)out_size; (void)ws_size;
  const float* x           = (const float*)d_in[0];
  const int*   mask        = (const int*)d_in[1];
  const int*   mem_mask    = (const int*)d_in[3];
  const float* cache_key   = (const float*)d_in[4];
  const float* cache_value = (const float*)d_in[5];
  const int*   cache_mask  = (const int*)d_in[6];
  const float* rel_emb     = (const float*)d_in[7];
  const float* Wq          = (const float*)d_in[8];
  const float* Wk          = (const float*)d_in[9];
  const float* Wv          = (const float*)d_in[10];
  const float* Wr          = (const float*)d_in[11];
  const float* uvec        = (const float*)d_in[12];
  const float* vvec        = (const float*)d_in[13];
  const float* Wo          = (const float*)d_in[14];
  float* dout = (float*)d_out;

  char* W = (char*)d_ws;  // ~51.1 MB of workspace used
  u16* xbf   = (u16*)(W + (0u << 20));   // dead after projection GEMMs
  u16* relbf = (u16*)(W + (4u << 20));   // dead after projection GEMMs
  u16* pO    = (u16*)(W + (0u << 20));   // 16MB: overlays xbf,relbf,wt5[0..3]
  u16* wt5   = (u16*)(W + (8u << 20));   // q,k,v,r dead by attn; o at +8MB
  u16* kbuf  = (u16*)(W + (18u << 20));
  u16* vtbuf = (u16*)(W + (26u << 20));
  u16* rbuf  = (u16*)(W + (34u << 20));
  u16* qu    = (u16*)(W + (38u << 20));
  u16* qv    = (u16*)(W + (42u << 20));
  u16* obf   = (u16*)(W + (46u << 20));
  int* qseg  = (int*)(W + (50u << 20));
  int* kseg  = (int*)(W + (50u << 20) + 8192);
  float* pml = (float*)(W + (50u << 20) + 32768);

  prep_kernel<<<dim3(13314), dim3(256), 0, stream>>>(
      x, xbf, rel_emb, relbf, Wq, Wk, Wv, Wr, Wo, wt5, cache_key, kbuf,
      cache_value, vtbuf, mask, mem_mask, cache_mask, qseg, kseg);
  gemm_proj_kernel<<<dim3(8, 16, 4), dim3(256), 0, stream>>>(
      xbf, relbf, wt5, qu, qv, kbuf, vtbuf, rbuf, dout, uvec, vvec);
  attn_kernel<<<dim3(64, 32), dim3(256), 0, stream>>>(qu, qv, kbuf, vtbuf, rbuf,
                                                      qseg, kseg, pO, pml);
  combine_kernel<<<dim3(1024), dim3(256), 0, stream>>>(pO, pml, obf);
  gemm_o_kernel<<<dim3(16, 32), dim3(256), 0, stream>>>(obf, wt5 + (4u << 20), dout);
}